// Round 7
// baseline (310.183 us; speedup 1.0000x reference)
//
#include <hip/hip_runtime.h>
#include <math.h>

#define VN 16
#define TN 2048
#define NROWS (VN*TN)   // 32768
#define DIN 64
#define HID 128
#define DKD 48
#define KNB 33
#define BR 32           // rows per block for qkv/heads

// ---------------- Threefry-2x32, key = (0, 42) ----------------
__device__ __forceinline__ unsigned rotl32(unsigned x, int d){ return (x<<d)|(x>>(32-d)); }

__device__ __forceinline__ void tf2x32(unsigned c0, unsigned c1, unsigned& y0, unsigned& y1){
  const unsigned k0 = 0u, k1 = 42u;
  const unsigned k2 = k0 ^ k1 ^ 0x1BD11BDAu;
  unsigned x0 = c0, x1 = c1;
  x0 += k0; x1 += k1;
#define TF_R(r) { x0 += x1; x1 = rotl32(x1,(r)); x1 ^= x0; }
  TF_R(13) TF_R(15) TF_R(26) TF_R(6)   x0 += k1; x1 += k2 + 1u;
  TF_R(17) TF_R(29) TF_R(16) TF_R(24)  x0 += k2; x1 += k0 + 2u;
  TF_R(13) TF_R(15) TF_R(26) TF_R(6)   x0 += k0; x1 += k1 + 3u;
  TF_R(17) TF_R(29) TF_R(16) TF_R(24)  x0 += k1; x1 += k2 + 4u;
  TF_R(13) TF_R(15) TF_R(26) TF_R(6)   x0 += k2; x1 += k0 + 5u;
#undef TF_R
  y0 = x0; y1 = x1;
}

__device__ __forceinline__ double md64_of(const float* __restrict__ max_depth, int n){
  unsigned y0, y1;
  tf2x32(0u, (unsigned)n, y0, y1);
  unsigned long long bits = (((unsigned long long)y0) << 32) | (unsigned long long)y1;
  unsigned long long fb = (bits >> 12) | 0x3FF0000000000000ull;   // [1,2)
  double f; __builtin_memcpy(&f, &fb, 8);
  f -= 1.0;
  return (double)max_depth[n] + f * (1.0/8192.0);
}

// ---------------- weight f32 -> f64 prep ----------------
// segments (doubles): Wq1 8192 | Wk1 8192 | Wv1 8192 | Wq2 6144 | Wk2 6144 | Wv2 6144
//                   | Wd1 14336 | Wm1 8192 | Wd2 256 | Wm2 256   (total 66048)
#define NWD 66048
struct WPtrs { const float* s0; const float* s1; const float* s2; const float* s3;
               const float* s4; const float* s5; const float* s6; const float* s7;
               const float* s8; const float* s9; };

__global__ void prep_kernel(WPtrs p, double* __restrict__ dst){
  int n = blockIdx.x*blockDim.x + threadIdx.x;
  if (n >= NWD) return;
  const int sz[10]  = {8192,8192,8192,6144,6144,6144,14336,8192,256,256};
  const float* src[10] = {p.s0,p.s1,p.s2,p.s3,p.s4,p.s5,p.s6,p.s7,p.s8,p.s9};
  int off = n, seg = 0;
  #pragma unroll
  for (int s=0;s<9;s++){ if (off >= sz[seg]) { off -= sz[seg]; seg++; } }
  dst[n] = (double)src[seg][off];
}

// ---------------- q/k/v MLPs: 64 -> relu(128) -> 48, f64 weights, zero-cvt loops ----------------
__global__ __launch_bounds__(256) void qkv_kernel(const float* __restrict__ enc,
    const double* __restrict__ dW,
    const float* __restrict__ bq1, const float* __restrict__ bq2,
    const float* __restrict__ bk1, const float* __restrict__ bk2,
    const float* __restrict__ bv1, const float* __restrict__ bv2,
    float* __restrict__ qo, float* __restrict__ ko, float* __restrict__ vo)
{
  __shared__ double s_x[DIN][BR+2];    // 17.4 KB, row = 272B (16B aligned)
  __shared__ double s_h[HID][BR+2];    // 34.8 KB
  int tid = threadIdx.x;
  int base = blockIdx.x * BR;
  for (int idx = tid; idx < BR*DIN; idx += 256){
    int r = idx >> 6, c = idx & 63;
    s_x[c][r] = (double)enc[(size_t)(base+r)*DIN + c];
  }
  __syncthreads();

  const double* W1s[3] = {dW,         dW + 8192,  dW + 16384};
  const double* W2s[3] = {dW + 24576, dW + 30720, dW + 36864};
  const float* b1s[3] = {bq1, bk1, bv1};
  const float* b2s[3] = {bq2, bk2, bv2};
  float* outs[3] = {qo, ko, vo};

  const int u0  = (tid & 31) * 4;   // layer1: 4 hidden units
  const int r0  = (tid >> 5) * 4;   // layer1: 4 rows
  const int uo0 = (tid & 15) * 3;   // layer2: 3 outputs
  const int rr0 = (tid >> 4) * 2;   // layer2: 2 rows

  for (int mm = 0; mm < 3; mm++){
    const double* __restrict__ W1 = W1s[mm];
    const float*  __restrict__ b1 = b1s[mm];
    double acc[4][4];
    {
      double b0=(double)b1[u0], bb1=(double)b1[u0+1], b2=(double)b1[u0+2], b3=(double)b1[u0+3];
      #pragma unroll
      for (int r=0;r<4;r++){ acc[r][0]=b0; acc[r][1]=bb1; acc[r][2]=b2; acc[r][3]=b3; }
    }
    #pragma unroll 4
    for (int i=0;i<DIN;i++){
      const double2 x01 = *reinterpret_cast<const double2*>(&s_x[i][r0]);
      const double2 x23 = *reinterpret_cast<const double2*>(&s_x[i][r0+2]);
      const double2 w01 = *reinterpret_cast<const double2*>(&W1[i*HID + u0]);
      const double2 w23 = *reinterpret_cast<const double2*>(&W1[i*HID + u0 + 2]);
      double xd[4] = {x01.x, x01.y, x23.x, x23.y};
      double wd[4] = {w01.x, w01.y, w23.x, w23.y};
      #pragma unroll
      for (int r=0;r<4;r++)
        #pragma unroll
        for (int j=0;j<4;j++)
          acc[r][j] = fma(xd[r], wd[j], acc[r][j]);
    }
    #pragma unroll
    for (int j=0;j<4;j++){
      double2 h01; h01.x = fmax(acc[0][j],0.0); h01.y = fmax(acc[1][j],0.0);
      double2 h23; h23.x = fmax(acc[2][j],0.0); h23.y = fmax(acc[3][j],0.0);
      *reinterpret_cast<double2*>(&s_h[u0+j][r0])   = h01;
      *reinterpret_cast<double2*>(&s_h[u0+j][r0+2]) = h23;
    }
    __syncthreads();

    // layer2: 2 rows x 3 outputs per thread
    const double* __restrict__ W2 = W2s[mm];
    const float*  __restrict__ b2p = b2s[mm];
    double a[2][3];
    {
      double c0=(double)b2p[uo0], c1=(double)b2p[uo0+1], c2=(double)b2p[uo0+2];
      a[0][0]=c0; a[0][1]=c1; a[0][2]=c2;
      a[1][0]=c0; a[1][1]=c1; a[1][2]=c2;
    }
    #pragma unroll 4
    for (int i=0;i<HID;i++){
      const double2 hv = *reinterpret_cast<const double2*>(&s_h[i][rr0]);
      double w0 = W2[i*DKD+uo0], w1 = W2[i*DKD+uo0+1], w2 = W2[i*DKD+uo0+2];
      a[0][0]=fma(hv.x,w0,a[0][0]); a[0][1]=fma(hv.x,w1,a[0][1]); a[0][2]=fma(hv.x,w2,a[0][2]);
      a[1][0]=fma(hv.y,w0,a[1][0]); a[1][1]=fma(hv.y,w1,a[1][1]); a[1][2]=fma(hv.y,w2,a[1][2]);
    }
    {
      float* op = outs[mm] + (size_t)(base+rr0)*DKD;
      op[uo0]=(float)a[0][0]; op[uo0+1]=(float)a[0][1]; op[uo0+2]=(float)a[0][2];
      op[DKD+uo0]=(float)a[1][0]; op[DKD+uo0+1]=(float)a[1][1]; op[DKD+uo0+2]=(float)a[1][2];
    }
    __syncthreads();
  }
}

// ---------------- attention: 4 rows/block (1 wave each), f64 math, fused jitter ----------------
__global__ void attn_kernel(const float* __restrict__ qv, const float* __restrict__ kv,
    const float* __restrict__ vv, const float* __restrict__ role_emb,
    const float* __restrict__ max_depth,
    const int* __restrict__ prev_values, const int* __restrict__ next_values,
    const int* __restrict__ window_indices, const int* __restrict__ indices,
    const float* __restrict__ prev_mask, const float* __restrict__ next_mask,
    const float* __restrict__ window_mask,
    float* __restrict__ ctx_out)
{
  __shared__ float  s_q[4][DKD];
  __shared__ double s_p[4][KNB];
  __shared__ int    s_idx[4][KNB];
  int tid  = threadIdx.x;          // 256
  int wid  = tid >> 6;             // wave 0..3
  int lane = tid & 63;
  int n = blockIdx.x*4 + wid;
  int vrow = n >> 11;              // T = 2048
  int t    = n & 2047;

  if (lane < DKD) s_q[wid][lane] = qv[(size_t)n*DKD + lane];

  int v2l = lane & 15;
  double md_m = md64_of(max_depth, v2l*TN + t);
  double md_n = __shfl(md_m, 16 + vrow, 64);
  __syncthreads();

  double sc = -INFINITY;
  if (lane < KNB){
    int idx, role; bool valid;
    if (lane < 16){
      int m = lane*TN + t;
      idx   = prev_values[m];
      role  = (vrow<<4) + lane;
      valid = (prev_mask[m] == 0.0f);
    } else if (lane < 32){
      int v2 = lane - 16;
      int m = v2*TN + t;
      bool comp = md_n > md_m;       // exact f64 comparison (np-ref semantics)
      idx   = comp ? indices[m] : next_values[m];
      role  = 256 + (vrow<<4) + v2;
      valid = comp || (next_mask[m] == 0.0f);
    } else {
      idx   = window_indices[n];
      role  = 512 + vrow;
      valid = (window_mask[n] == 0.0f);
    }
    s_idx[wid][lane] = idx;
    const float4* kp = reinterpret_cast<const float4*>(kv + (size_t)idx*DKD);
    const float4* rp = reinterpret_cast<const float4*>(role_emb + (size_t)role*DKD);
    double acc = 0.0;
    #pragma unroll
    for (int d4 = 0; d4 < DKD/4; d4++){
      float4 kk = kp[d4], rr = rp[d4];
      acc = fma((double)s_q[wid][4*d4+0], (double)kk.x + (double)rr.x, acc);
      acc = fma((double)s_q[wid][4*d4+1], (double)kk.y + (double)rr.y, acc);
      acc = fma((double)s_q[wid][4*d4+2], (double)kk.z + (double)rr.z, acc);
      acc = fma((double)s_q[wid][4*d4+3], (double)kk.w + (double)rr.w, acc);
    }
    sc = acc / sqrt(48.0);
    if (!valid) sc = -1e9;
  }
  double mx = sc;
  #pragma unroll
  for (int o=32;o>0;o>>=1) mx = fmax(mx, __shfl_xor(mx, o, 64));
  double e = (lane < KNB) ? exp(sc - mx) : 0.0;
  double ssum = e;
  #pragma unroll
  for (int o=32;o>0;o>>=1) ssum += __shfl_xor(ssum, o, 64);
  if (lane < KNB) s_p[wid][lane] = e / ssum;
  __syncthreads();

  if (lane < DKD){
    double c = 0.0;
    for (int j=0;j<KNB;j++)
      c = fma(s_p[wid][j], (double)vv[(size_t)s_idx[wid][j]*DKD + lane], c);
    ctx_out[(size_t)n*DKD + lane] = (float)c;
  }
}

// ---------------- heads: dp (112->128->2), mp (64->128->2), NLL, f64 weights ----------------
__device__ __forceinline__ double nlogp_d(double x, double mu, double ls){
  double sp = fmax(ls, 0.0) + log1p(exp(-fabs(ls)));
  double s = sp + 1e-3;
  double z = (x - mu) / s;
  return 0.5*z*z + log(s) + 0.9189385332046727417803297; // 0.5*log(2*pi)
}

__global__ __launch_bounds__(256) void heads_kernel(const float* __restrict__ enc,
    const float* __restrict__ ctx, const float* __restrict__ uu,
    const double* __restrict__ dW,
    const float* __restrict__ bd1, const float* __restrict__ bd2,
    const float* __restrict__ bm1, const float* __restrict__ bm2,
    float* __restrict__ out)
{
  __shared__ double s_x[DIN+DKD][BR+2];  // [112][34] f64, 30.5 KB
  __shared__ float s_hd[HID][BR+2];      // 17.4 KB
  __shared__ float s_hm[HID][BR+2];      // 17.4 KB
  int tid = threadIdx.x;     // 256
  int base = blockIdx.x * BR;

  const double* __restrict__ Wd1 = dW + 43008;
  const double* __restrict__ Wm1 = dW + 57344;
  const double* __restrict__ Wd2 = dW + 65536;
  const double* __restrict__ Wm2 = dW + 65792;

  for (int idx = tid; idx < BR*DIN; idx += 256){
    int r = idx >> 6, c = idx & 63;
    s_x[c][r] = (double)enc[(size_t)(base+r)*DIN + c];
  }
  for (int idx = tid; idx < BR*DKD; idx += 256){
    int r = idx / DKD, c = idx - r*DKD;
    s_x[DIN + c][r] = (double)ctx[(size_t)(base+r)*DKD + c];
  }
  __syncthreads();

  const int u0 = (tid & 31) * 4;
  const int r0 = (tid >> 5) * 4;

  // dp hidden: 112 -> 128
  {
    double acc[4][4];
    double b0=(double)bd1[u0], b1=(double)bd1[u0+1], b2=(double)bd1[u0+2], b3=(double)bd1[u0+3];
    #pragma unroll
    for (int r=0;r<4;r++){ acc[r][0]=b0; acc[r][1]=b1; acc[r][2]=b2; acc[r][3]=b3; }
    #pragma unroll 4
    for (int i=0;i<DIN+DKD;i++){
      const double2 x01 = *reinterpret_cast<const double2*>(&s_x[i][r0]);
      const double2 x23 = *reinterpret_cast<const double2*>(&s_x[i][r0+2]);
      const double2 w01 = *reinterpret_cast<const double2*>(&Wd1[i*HID + u0]);
      const double2 w23 = *reinterpret_cast<const double2*>(&Wd1[i*HID + u0 + 2]);
      double xd[4] = {x01.x, x01.y, x23.x, x23.y};
      double wd[4] = {w01.x, w01.y, w23.x, w23.y};
      #pragma unroll
      for (int r=0;r<4;r++)
        #pragma unroll
        for (int j=0;j<4;j++)
          acc[r][j] = fma(xd[r], wd[j], acc[r][j]);
    }
    #pragma unroll
    for (int j=0;j<4;j++){
      float4 hv;
      hv.x=(float)fmax(acc[0][j],0.0); hv.y=(float)fmax(acc[1][j],0.0);
      hv.z=(float)fmax(acc[2][j],0.0); hv.w=(float)fmax(acc[3][j],0.0);
      *reinterpret_cast<float4*>(&s_hd[u0+j][r0]) = hv;
    }
  }
  // mp hidden: 64 -> 128
  {
    double acc[4][4];
    double b0=(double)bm1[u0], b1=(double)bm1[u0+1], b2=(double)bm1[u0+2], b3=(double)bm1[u0+3];
    #pragma unroll
    for (int r=0;r<4;r++){ acc[r][0]=b0; acc[r][1]=b1; acc[r][2]=b2; acc[r][3]=b3; }
    #pragma unroll 4
    for (int i=0;i<DIN;i++){
      const double2 x01 = *reinterpret_cast<const double2*>(&s_x[i][r0]);
      const double2 x23 = *reinterpret_cast<const double2*>(&s_x[i][r0+2]);
      const double2 w01 = *reinterpret_cast<const double2*>(&Wm1[i*HID + u0]);
      const double2 w23 = *reinterpret_cast<const double2*>(&Wm1[i*HID + u0 + 2]);
      double xd[4] = {x01.x, x01.y, x23.x, x23.y};
      double wd[4] = {w01.x, w01.y, w23.x, w23.y};
      #pragma unroll
      for (int r=0;r<4;r++)
        #pragma unroll
        for (int j=0;j<4;j++)
          acc[r][j] = fma(xd[r], wd[j], acc[r][j]);
    }
    #pragma unroll
    for (int j=0;j<4;j++){
      float4 hv;
      hv.x=(float)fmax(acc[0][j],0.0); hv.y=(float)fmax(acc[1][j],0.0);
      hv.z=(float)fmax(acc[2][j],0.0); hv.w=(float)fmax(acc[3][j],0.0);
      *reinterpret_cast<float4*>(&s_hm[u0+j][r0]) = hv;
    }
  }
  __syncthreads();

  // layer2 + NLL: tid = r*8 + which*4 + o*2 + part
  {
    int r     = tid >> 3;         // 0..31
    int which = (tid >> 2) & 1;   // 0: dp, 1: mp
    int o     = (tid >> 1) & 1;
    int part  = tid & 1;
    const float*  __restrict__ hb = which ? &s_hm[0][0] : &s_hd[0][0];
    const double* __restrict__ W2 = which ? Wm2 : Wd2;
    double acc2 = part ? 0.0 : (double)(which ? bm2[o] : bd2[o]);
    int i0 = part*64;
    #pragma unroll 4
    for (int ii=0; ii<64; ii++){
      int i = i0 + ii;
      acc2 = fma((double)hb[i*(BR+2) + r], W2[i*2 + o], acc2);
    }
    acc2 += __shfl_xor(acc2, 1, 64);           // combine halves
    double other = __shfl_xor(acc2, 2, 64);    // exchange mu <-> log_s
    double mu = (o==0) ? acc2  : other;
    double ls = (o==0) ? other : acc2;
    double x  = (double)uu[base + r];
    double nl = nlogp_d(x, mu, ls);
    double tot = nl + __shfl_xor(nl, 4, 64);   // dp + mp
    if ((tid & 7) == 0) out[base + r] = (float)tot;
  }
}

extern "C" void kernel_launch(void* const* d_in, const int* in_sizes, int n_in,
                              void* d_out, int out_size, void* d_ws, size_t ws_size,
                              hipStream_t stream) {
  const float* encoded = (const float*)d_in[0];
  const float* u       = (const float*)d_in[1];
  const float* Wq1 = (const float*)d_in[2];  const float* bq1 = (const float*)d_in[3];
  const float* Wq2 = (const float*)d_in[4];  const float* bq2 = (const float*)d_in[5];
  const float* Wk1 = (const float*)d_in[6];  const float* bk1 = (const float*)d_in[7];
  const float* Wk2 = (const float*)d_in[8];  const float* bk2 = (const float*)d_in[9];
  const float* Wv1 = (const float*)d_in[10]; const float* bv1 = (const float*)d_in[11];
  const float* Wv2 = (const float*)d_in[12]; const float* bv2 = (const float*)d_in[13];
  const float* role_emb = (const float*)d_in[14];
  const float* Wd1 = (const float*)d_in[15]; const float* bd1 = (const float*)d_in[16];
  const float* Wd2 = (const float*)d_in[17]; const float* bd2 = (const float*)d_in[18];
  const float* Wm1 = (const float*)d_in[19]; const float* bm1 = (const float*)d_in[20];
  const float* Wm2 = (const float*)d_in[21]; const float* bm2 = (const float*)d_in[22];
  const int*   prev_values    = (const int*)d_in[23];
  const int*   next_values    = (const int*)d_in[24];
  const int*   window_indices = (const int*)d_in[25];
  const int*   indices        = (const int*)d_in[26];
  const float* prev_mask   = (const float*)d_in[27];
  const float* next_mask   = (const float*)d_in[28];
  const float* window_mask = (const float*)d_in[29];
  const float* max_depth   = (const float*)d_in[30];
  float* out = (float*)d_out;

  double* dW = (double*)d_ws;                 // 66048 doubles (528 KB)
  float* q  = (float*)(dW + NWD);
  float* k  = q  + (size_t)NROWS*DKD;
  float* v  = k  + (size_t)NROWS*DKD;
  float* cx = v  + (size_t)NROWS*DKD;

  WPtrs wp = {Wq1, Wk1, Wv1, Wq2, Wk2, Wv2, Wd1, Wm1, Wd2, Wm2};
  prep_kernel<<<(NWD+255)/256, 256, 0, stream>>>(wp, dW);
  qkv_kernel<<<NROWS/BR, 256, 0, stream>>>(encoded, dW,
      bq1,bq2, bk1,bk2, bv1,bv2, q, k, v);
  attn_kernel<<<NROWS/4, 256, 0, stream>>>(q, k, v, role_emb, max_depth,
      prev_values, next_values, window_indices, indices,
      prev_mask, next_mask, window_mask, cx);
  heads_kernel<<<NROWS/BR, 256, 0, stream>>>(encoded, cx, u, dW,
      bd1,bd2, bm1,bm2, out);
}

// Round 8
// 192.153 us; speedup vs baseline: 1.6143x; 1.6143x over previous
//
#include <hip/hip_runtime.h>
#include <math.h>

#define VN 16
#define TN 2048
#define NROWS (VN*TN)   // 32768
#define DIN 64
#define HID 128
#define DKD 48
#define KNB 33
#define BR 32           // rows per block for qkv/heads

// ---------------- Threefry-2x32, key = (0, 42) ----------------
__device__ __forceinline__ unsigned rotl32(unsigned x, int d){ return (x<<d)|(x>>(32-d)); }

__device__ __forceinline__ void tf2x32(unsigned c0, unsigned c1, unsigned& y0, unsigned& y1){
  const unsigned k0 = 0u, k1 = 42u;
  const unsigned k2 = k0 ^ k1 ^ 0x1BD11BDAu;
  unsigned x0 = c0, x1 = c1;
  x0 += k0; x1 += k1;
#define TF_R(r) { x0 += x1; x1 = rotl32(x1,(r)); x1 ^= x0; }
  TF_R(13) TF_R(15) TF_R(26) TF_R(6)   x0 += k1; x1 += k2 + 1u;
  TF_R(17) TF_R(29) TF_R(16) TF_R(24)  x0 += k2; x1 += k0 + 2u;
  TF_R(13) TF_R(15) TF_R(26) TF_R(6)   x0 += k0; x1 += k1 + 3u;
  TF_R(17) TF_R(29) TF_R(16) TF_R(24)  x0 += k1; x1 += k2 + 4u;
  TF_R(13) TF_R(15) TF_R(26) TF_R(6)   x0 += k2; x1 += k0 + 5u;
#undef TF_R
  y0 = x0; y1 = x1;
}

// exact f64 md for element n (partitionable 64-bit threefry stream, np-ref semantics)
__device__ __forceinline__ double md64_of(const float* __restrict__ max_depth, int n){
  unsigned y0, y1;
  tf2x32(0u, (unsigned)n, y0, y1);
  unsigned long long bits = (((unsigned long long)y0) << 32) | (unsigned long long)y1;
  unsigned long long fb = (bits >> 12) | 0x3FF0000000000000ull;   // [1,2)
  double f; __builtin_memcpy(&f, &fb, 8);
  f -= 1.0;
  return (double)max_depth[n] + f * (1.0/8192.0);
}

// ---------------- q/k/v MLPs: 64 -> relu(128) -> 48, f32, register-tiled ----------------
// 256 threads, 32 rows/block. L1: thread tile 4 rows x 4 units.
// Per i: 1 float4 LDS read + 1 float4 global read -> 16 f32 FMA (zero cvt).
__global__ __launch_bounds__(256) void qkv_kernel(const float* __restrict__ enc,
    const float* __restrict__ Wq1, const float* __restrict__ bq1,
    const float* __restrict__ Wq2, const float* __restrict__ bq2,
    const float* __restrict__ Wk1, const float* __restrict__ bk1,
    const float* __restrict__ Wk2, const float* __restrict__ bk2,
    const float* __restrict__ Wv1, const float* __restrict__ bv1,
    const float* __restrict__ Wv2, const float* __restrict__ bv2,
    float* __restrict__ qo, float* __restrict__ ko, float* __restrict__ vo)
{
  __shared__ float s_x[DIN][BR+4];    // i-major, row=144B
  __shared__ float s_h[HID][BR+2];    // i-major, row=136B
  int tid = threadIdx.x;
  int base = blockIdx.x * BR;
  for (int idx = tid; idx < BR*DIN; idx += 256){
    int r = idx >> 6, c = idx & 63;
    s_x[c][r] = enc[(size_t)(base+r)*DIN + c];
  }
  __syncthreads();

  const float* W1s[3] = {Wq1, Wk1, Wv1};
  const float* b1s[3] = {bq1, bk1, bv1};
  const float* W2s[3] = {Wq2, Wk2, Wv2};
  const float* b2s[3] = {bq2, bk2, bv2};
  float* outs[3] = {qo, ko, vo};

  const int u0  = (tid & 31) * 4;   // layer1: 4 hidden units
  const int r0  = (tid >> 5) * 4;   // layer1: 4 rows
  const int uo0 = (tid & 15) * 3;   // layer2: 3 outputs
  const int rr0 = (tid >> 4) * 2;   // layer2: 2 rows

  for (int mm = 0; mm < 3; mm++){
    const float* __restrict__ W1 = W1s[mm];
    const float* __restrict__ b1 = b1s[mm];
    float acc[4][4];
    {
      float b0=b1[u0], bb1=b1[u0+1], b2=b1[u0+2], b3=b1[u0+3];
      #pragma unroll
      for (int r=0;r<4;r++){ acc[r][0]=b0; acc[r][1]=bb1; acc[r][2]=b2; acc[r][3]=b3; }
    }
    #pragma unroll 4
    for (int i=0;i<DIN;i++){
      const float4 xv = *reinterpret_cast<const float4*>(&s_x[i][r0]);
      const float4 wv = *reinterpret_cast<const float4*>(&W1[i*HID + u0]);
      float xd[4] = {xv.x, xv.y, xv.z, xv.w};
      float wd[4] = {wv.x, wv.y, wv.z, wv.w};
      #pragma unroll
      for (int r=0;r<4;r++)
        #pragma unroll
        for (int j=0;j<4;j++)
          acc[r][j] = fmaf(xd[r], wd[j], acc[r][j]);
    }
    #pragma unroll
    for (int j=0;j<4;j++){
      float4 hv;
      hv.x = fmaxf(acc[0][j], 0.0f);
      hv.y = fmaxf(acc[1][j], 0.0f);
      hv.z = fmaxf(acc[2][j], 0.0f);
      hv.w = fmaxf(acc[3][j], 0.0f);
      *reinterpret_cast<float4*>(&s_h[u0+j][r0]) = hv;
    }
    __syncthreads();

    // layer2: 2 rows x 3 outputs per thread
    const float* __restrict__ W2 = W2s[mm];
    const float* __restrict__ b2p = b2s[mm];
    float a[2][3];
    {
      float c0=b2p[uo0], c1=b2p[uo0+1], c2=b2p[uo0+2];
      a[0][0]=c0; a[0][1]=c1; a[0][2]=c2;
      a[1][0]=c0; a[1][1]=c1; a[1][2]=c2;
    }
    #pragma unroll 4
    for (int i=0;i<HID;i++){
      const float2 hv = *reinterpret_cast<const float2*>(&s_h[i][rr0]);
      float h0 = hv.x, h1 = hv.y;
      float w0 = W2[i*DKD+uo0], w1 = W2[i*DKD+uo0+1], w2 = W2[i*DKD+uo0+2];
      a[0][0]=fmaf(h0,w0,a[0][0]); a[0][1]=fmaf(h0,w1,a[0][1]); a[0][2]=fmaf(h0,w2,a[0][2]);
      a[1][0]=fmaf(h1,w0,a[1][0]); a[1][1]=fmaf(h1,w1,a[1][1]); a[1][2]=fmaf(h1,w2,a[1][2]);
    }
    {
      float* op = outs[mm] + (size_t)(base+rr0)*DKD;
      op[uo0]=a[0][0]; op[uo0+1]=a[0][1]; op[uo0+2]=a[0][2];
      op[DKD+uo0]=a[1][0]; op[DKD+uo0+1]=a[1][1]; op[DKD+uo0+2]=a[1][2];
    }
    __syncthreads();
  }
}

// ---------------- attention: 4 rows/block (1 wave each), f32 scores/PV, f64 comp+softmax ----------------
__global__ void attn_kernel(const float* __restrict__ qv, const float* __restrict__ kv,
    const float* __restrict__ vv, const float* __restrict__ role_emb,
    const float* __restrict__ max_depth,
    const int* __restrict__ prev_values, const int* __restrict__ next_values,
    const int* __restrict__ window_indices, const int* __restrict__ indices,
    const float* __restrict__ prev_mask, const float* __restrict__ next_mask,
    const float* __restrict__ window_mask,
    float* __restrict__ ctx_out)
{
  __shared__ float s_q[4][DKD];
  __shared__ float s_p[4][KNB];
  __shared__ int   s_idx[4][KNB];
  int tid  = threadIdx.x;          // 256
  int wid  = tid >> 6;             // wave 0..3
  int lane = tid & 63;
  int n = blockIdx.x*4 + wid;
  int vrow = n >> 11;              // T = 2048
  int t    = n & 2047;

  if (lane < DKD) s_q[wid][lane] = qv[(size_t)n*DKD + lane];

  int v2l = lane & 15;
  double md_m = md64_of(max_depth, v2l*TN + t);
  double md_n = __shfl(md_m, 16 + vrow, 64);
  __syncthreads();

  float sc = -INFINITY;
  if (lane < KNB){
    int idx, role; bool valid;
    if (lane < 16){
      int m = lane*TN + t;
      idx   = prev_values[m];
      role  = (vrow<<4) + lane;
      valid = (prev_mask[m] == 0.0f);
    } else if (lane < 32){
      int v2 = lane - 16;
      int m = v2*TN + t;
      bool comp = md_n > md_m;       // exact f64 comparison (np-ref semantics)
      idx   = comp ? indices[m] : next_values[m];
      role  = 256 + (vrow<<4) + v2;
      valid = comp || (next_mask[m] == 0.0f);
    } else {
      idx   = window_indices[n];
      role  = 512 + vrow;
      valid = (window_mask[n] == 0.0f);
    }
    s_idx[wid][lane] = idx;
    const float4* kp = reinterpret_cast<const float4*>(kv + (size_t)idx*DKD);
    const float4* rp = reinterpret_cast<const float4*>(role_emb + (size_t)role*DKD);
    float acc = 0.0f;
    #pragma unroll
    for (int d4 = 0; d4 < DKD/4; d4++){
      float4 kk = kp[d4], rr = rp[d4];
      acc = fmaf(s_q[wid][4*d4+0], kk.x + rr.x, acc);
      acc = fmaf(s_q[wid][4*d4+1], kk.y + rr.y, acc);
      acc = fmaf(s_q[wid][4*d4+2], kk.z + rr.z, acc);
      acc = fmaf(s_q[wid][4*d4+3], kk.w + rr.w, acc);
    }
    sc = acc / 6.928203230275509f;   // sqrt(48)
    if (!valid) sc = -1e9f;
  }
  // per-wave softmax over lanes 0..32 (f64 exp chain for accuracy, cheap)
  float mx = sc;
  #pragma unroll
  for (int o=32;o>0;o>>=1) mx = fmaxf(mx, __shfl_xor(mx, o, 64));
  double e = (lane < KNB) ? exp((double)sc - (double)mx) : 0.0;
  double ssum = e;
  #pragma unroll
  for (int o=32;o>0;o>>=1) ssum += __shfl_xor(ssum, o, 64);
  if (lane < KNB) s_p[wid][lane] = (float)(e / ssum);
  __syncthreads();

  if (lane < DKD){
    float c = 0.0f;
    for (int j=0;j<KNB;j++)
      c = fmaf(s_p[wid][j], vv[(size_t)s_idx[wid][j]*DKD + lane], c);
    ctx_out[(size_t)n*DKD + lane] = c;
  }
}

// ---------------- heads: dp (112->128->2), mp (64->128->2), f32 MLP + f64 NLL ----------------
__device__ __forceinline__ double nlogp_d(double x, double mu, double ls){
  double sp = fmax(ls, 0.0) + log1p(exp(-fabs(ls)));
  double s = sp + 1e-3;
  double z = (x - mu) / s;
  return 0.5*z*z + log(s) + 0.9189385332046727417803297; // 0.5*log(2*pi)
}

__global__ __launch_bounds__(256) void heads_kernel(const float* __restrict__ enc,
    const float* __restrict__ ctx, const float* __restrict__ uu,
    const float* __restrict__ Wd1, const float* __restrict__ bd1,
    const float* __restrict__ Wd2, const float* __restrict__ bd2,
    const float* __restrict__ Wm1, const float* __restrict__ bm1,
    const float* __restrict__ Wm2, const float* __restrict__ bm2,
    float* __restrict__ out)
{
  __shared__ float s_x[DIN+DKD][BR+4];   // [112][36] i-major
  __shared__ float s_hd[HID][BR+2];      // [128][34]
  __shared__ float s_hm[HID][BR+2];
  int tid = threadIdx.x;     // 256
  int base = blockIdx.x * BR;

  for (int idx = tid; idx < BR*DIN; idx += 256){
    int r = idx >> 6, c = idx & 63;
    s_x[c][r] = enc[(size_t)(base+r)*DIN + c];
  }
  for (int idx = tid; idx < BR*DKD; idx += 256){
    int r = idx / DKD, c = idx - r*DKD;
    s_x[DIN + c][r] = ctx[(size_t)(base+r)*DKD + c];
  }
  __syncthreads();

  const int u0 = (tid & 31) * 4;
  const int r0 = (tid >> 5) * 4;

  // dp hidden: 112 -> 128
  {
    float acc[4][4];
    float b0=bd1[u0], b1=bd1[u0+1], b2=bd1[u0+2], b3=bd1[u0+3];
    #pragma unroll
    for (int r=0;r<4;r++){ acc[r][0]=b0; acc[r][1]=b1; acc[r][2]=b2; acc[r][3]=b3; }
    #pragma unroll 4
    for (int i=0;i<DIN+DKD;i++){
      const float4 xv = *reinterpret_cast<const float4*>(&s_x[i][r0]);
      const float4 wv = *reinterpret_cast<const float4*>(&Wd1[i*HID + u0]);
      float xd[4] = {xv.x, xv.y, xv.z, xv.w};
      float wd[4] = {wv.x, wv.y, wv.z, wv.w};
      #pragma unroll
      for (int r=0;r<4;r++)
        #pragma unroll
        for (int j=0;j<4;j++)
          acc[r][j] = fmaf(xd[r], wd[j], acc[r][j]);
    }
    #pragma unroll
    for (int j=0;j<4;j++){
      float4 hv;
      hv.x=fmaxf(acc[0][j],0.0f); hv.y=fmaxf(acc[1][j],0.0f);
      hv.z=fmaxf(acc[2][j],0.0f); hv.w=fmaxf(acc[3][j],0.0f);
      *reinterpret_cast<float4*>(&s_hd[u0+j][r0]) = hv;
    }
  }
  // mp hidden: 64 -> 128
  {
    float acc[4][4];
    float b0=bm1[u0], b1=bm1[u0+1], b2=bm1[u0+2], b3=bm1[u0+3];
    #pragma unroll
    for (int r=0;r<4;r++){ acc[r][0]=b0; acc[r][1]=b1; acc[r][2]=b2; acc[r][3]=b3; }
    #pragma unroll 4
    for (int i=0;i<DIN;i++){
      const float4 xv = *reinterpret_cast<const float4*>(&s_x[i][r0]);
      const float4 wv = *reinterpret_cast<const float4*>(&Wm1[i*HID + u0]);
      float xd[4] = {xv.x, xv.y, xv.z, xv.w};
      float wd[4] = {wv.x, wv.y, wv.z, wv.w};
      #pragma unroll
      for (int r=0;r<4;r++)
        #pragma unroll
        for (int j=0;j<4;j++)
          acc[r][j] = fmaf(xd[r], wd[j], acc[r][j]);
    }
    #pragma unroll
    for (int j=0;j<4;j++){
      float4 hv;
      hv.x=fmaxf(acc[0][j],0.0f); hv.y=fmaxf(acc[1][j],0.0f);
      hv.z=fmaxf(acc[2][j],0.0f); hv.w=fmaxf(acc[3][j],0.0f);
      *reinterpret_cast<float4*>(&s_hm[u0+j][r0]) = hv;
    }
  }
  __syncthreads();

  // layer2 + NLL: tid = r*8 + which*4 + o*2 + part
  {
    int r     = tid >> 3;         // 0..31
    int which = (tid >> 2) & 1;   // 0: dp, 1: mp
    int o     = (tid >> 1) & 1;
    int part  = tid & 1;
    const float* __restrict__ hb = which ? &s_hm[0][0] : &s_hd[0][0];
    const float* __restrict__ W2 = which ? Wm2 : Wd2;
    float acc2 = part ? 0.0f : (which ? bm2[o] : bd2[o]);
    int i0 = part*64;
    #pragma unroll 4
    for (int ii=0; ii<64; ii++){
      int i = i0 + ii;
      acc2 = fmaf(hb[i*(BR+2) + r], W2[i*2 + o], acc2);
    }
    double accd = (double)acc2;
    accd += __shfl_xor(accd, 1, 64);           // combine halves
    double other = __shfl_xor(accd, 2, 64);    // exchange mu <-> log_s
    double mu = (o==0) ? accd  : other;
    double ls = (o==0) ? other : accd;
    double x  = (double)uu[base + r];
    double nl = nlogp_d(x, mu, ls);
    double tot = nl + __shfl_xor(nl, 4, 64);   // dp + mp
    if ((tid & 7) == 0) out[base + r] = (float)tot;
  }
}

extern "C" void kernel_launch(void* const* d_in, const int* in_sizes, int n_in,
                              void* d_out, int out_size, void* d_ws, size_t ws_size,
                              hipStream_t stream) {
  const float* encoded = (const float*)d_in[0];
  const float* u       = (const float*)d_in[1];
  const float* Wq1 = (const float*)d_in[2];  const float* bq1 = (const float*)d_in[3];
  const float* Wq2 = (const float*)d_in[4];  const float* bq2 = (const float*)d_in[5];
  const float* Wk1 = (const float*)d_in[6];  const float* bk1 = (const float*)d_in[7];
  const float* Wk2 = (const float*)d_in[8];  const float* bk2 = (const float*)d_in[9];
  const float* Wv1 = (const float*)d_in[10]; const float* bv1 = (const float*)d_in[11];
  const float* Wv2 = (const float*)d_in[12]; const float* bv2 = (const float*)d_in[13];
  const float* role_emb = (const float*)d_in[14];
  const float* Wd1 = (const float*)d_in[15]; const float* bd1 = (const float*)d_in[16];
  const float* Wd2 = (const float*)d_in[17]; const float* bd2 = (const float*)d_in[18];
  const float* Wm1 = (const float*)d_in[19]; const float* bm1 = (const float*)d_in[20];
  const float* Wm2 = (const float*)d_in[21]; const float* bm2 = (const float*)d_in[22];
  const int*   prev_values    = (const int*)d_in[23];
  const int*   next_values    = (const int*)d_in[24];
  const int*   window_indices = (const int*)d_in[25];
  const int*   indices        = (const int*)d_in[26];
  const float* prev_mask   = (const float*)d_in[27];
  const float* next_mask   = (const float*)d_in[28];
  const float* window_mask = (const float*)d_in[29];
  const float* max_depth   = (const float*)d_in[30];
  float* out = (float*)d_out;

  float* q  = (float*)d_ws;
  float* k  = q  + (size_t)NROWS*DKD;
  float* v  = k  + (size_t)NROWS*DKD;
  float* cx = v  + (size_t)NROWS*DKD;

  qkv_kernel<<<NROWS/BR, 256, 0, stream>>>(encoded,
      Wq1,bq1,Wq2,bq2, Wk1,bk1,Wk2,bk2, Wv1,bv1,Wv2,bv2, q, k, v);
  attn_kernel<<<NROWS/4, 256, 0, stream>>>(q, k, v, role_emb, max_depth,
      prev_values, next_values, window_indices, indices,
      prev_mask, next_mask, window_mask, cx);
  heads_kernel<<<NROWS/BR, 256, 0, stream>>>(encoded, cx, u,
      Wd1,bd1,Wd2,bd2, Wm1,bm1,Wm2,bm2, out);
}